// Round 15
// baseline (547.800 us; speedup 1.0000x reference)
//
#include <hip/hip_runtime.h>
#include <hip/hip_bf16.h>
#include <math.h>

#define Tn 1024
#define Bn 16
#define Hn 1024
#define Sn 2048

typedef __attribute__((ext_vector_type(8))) short bf16x8;
typedef __attribute__((ext_vector_type(8))) unsigned short u16x8;
typedef __attribute__((ext_vector_type(4))) float f32x4;

__device__ __forceinline__ unsigned short f2bf(float x) {
  unsigned u = __float_as_uint(x);
  u += 0x7fffu + ((u >> 16) & 1u);  // round-to-nearest-even to bf16
  return (unsigned short)(u >> 16);
}
__device__ __forceinline__ float bf2f(unsigned short h) {
  return __uint_as_float(((unsigned)h) << 16);
}

// async global->LDS, 16B per lane; LDS dest = wave-uniform base + lane*16
__device__ __forceinline__ void gload16(const void* g, void* l) {
  __builtin_amdgcn_global_load_lds((const __attribute__((address_space(1))) void*)g,
                                   (__attribute__((address_space(3))) void*)l, 16, 0, 0);
}

// XCD-chunked bijective blockIdx swizzle (nwg % 8 == 0)
__device__ __forceinline__ int xcd_swz(int bid, int nwg) {
  return (bid & 7) * (nwg >> 3) + (bid >> 3);
}

__device__ __forceinline__ f32x4 mfma16(bf16x8 a, bf16x8 b, f32x4 c) {
  return __builtin_amdgcn_mfma_f32_16x16x32_bf16(a, b, c, 0, 0, 0);
}

// ---------- conversion kernels ----------

__global__ __launch_bounds__(256) void k_split_plane(const float* __restrict__ src,
                                                     unsigned short* __restrict__ hiP,
                                                     unsigned short* __restrict__ loP,
                                                     int rows) {
  const int i = blockIdx.x * 256 + threadIdx.x;
  const int h8 = i & (Hn / 8 - 1);
  const int rem = i >> 7;
  const int b = rem & (Bn - 1);
  const int r = rem >> 4;
  const float4 a = *(const float4*)(src + (size_t)i * 8);
  const float4 c = *(const float4*)(src + (size_t)i * 8 + 4);
  const float v[8] = {a.x, a.y, a.z, a.w, c.x, c.y, c.z, c.w};
  u16x8 hv, lv;
#pragma unroll
  for (int j = 0; j < 8; ++j) {
    const unsigned short h = f2bf(v[j]);
    hv[j] = h;
    lv[j] = f2bf(v[j] - bf2f(h));
  }
  const size_t dst = ((size_t)b * rows + r) * Hn + h8 * 8;
  *(u16x8*)(hiP + dst) = hv;
  *(u16x8*)(loP + dst) = lv;
}

__global__ __launch_bounds__(256) void k_cvt8(const float* __restrict__ src,
                                              unsigned short* __restrict__ dst, int n8) {
  const int i = blockIdx.x * 256 + threadIdx.x;
  if (i >= n8) return;
  const float4 a = *(const float4*)(src + (size_t)i * 8);
  const float4 c = *(const float4*)(src + (size_t)i * 8 + 4);
  u16x8 u;
  u[0] = f2bf(a.x); u[1] = f2bf(a.y); u[2] = f2bf(a.z); u[3] = f2bf(a.w);
  u[4] = f2bf(c.x); u[5] = f2bf(c.y); u[6] = f2bf(c.z); u[7] = f2bf(c.w);
  *(u16x8*)(dst + (size_t)i * 8) = u;
}

// fused: mem (S,B,H) f32 -> memH/memL [B][S][H] bf16 + memT [B][H][S] bf16 (hi, transposed)
__global__ __launch_bounds__(256) void k_split_mem3(const float* __restrict__ mem,
                                                    unsigned short* __restrict__ memH,
                                                    unsigned short* __restrict__ memL,
                                                    unsigned short* __restrict__ memT) {
  __shared__ unsigned short L[64 * 72];
  const int t = threadIdx.x;
  const int h0 = blockIdx.x * 64, s0 = blockIdx.y * 64, b = blockIdx.z;
#pragma unroll
  for (int p = 0; p < 2; ++p) {
    const int id = p * 256 + t;
    const int row = id >> 3;  // s_l 0..63
    const int c8 = id & 7;    // 8-elem chunk along h
    const float* src = mem + ((size_t)(s0 + row) * Bn + b) * Hn + h0 + c8 * 8;
    const float4 a = *(const float4*)src;
    const float4 c = *(const float4*)(src + 4);
    const float v[8] = {a.x, a.y, a.z, a.w, c.x, c.y, c.z, c.w};
    u16x8 hv, lv;
#pragma unroll
    for (int j = 0; j < 8; ++j) {
      const unsigned short h = f2bf(v[j]);
      hv[j] = h;
      lv[j] = f2bf(v[j] - bf2f(h));
    }
    const size_t dst = ((size_t)b * Sn + s0 + row) * Hn + h0 + c8 * 8;
    *(u16x8*)(memH + dst) = hv;
    *(u16x8*)(memL + dst) = lv;
#pragma unroll
    for (int e0 = 0; e0 < 8; ++e0) {
      const int e = (e0 + (t >> 3)) & 7;  // bank stagger
      L[(c8 * 8 + e) * 72 + row] = hv[e];
    }
  }
  __syncthreads();
#pragma unroll
  for (int p = 0; p < 2; ++p) {
    const int cid = p * 256 + t;
    const int h_l = cid >> 3;
    const int c = cid & 7;
    const u16x8 vv = *(const u16x8*)&L[h_l * 72 + c * 8];
    *(u16x8*)(memT + ((size_t)b * Hn + h0 + h_l) * Sn + s0 + c * 8) = vv;
  }
}

// ---------- staging (linear LDS dest, XOR-swizzled global source) ----------

// 256 rows x 32 cols bf16 (64B rows). swizzle: cbyte ^= (row&8)<<2 (measured 0-conflict)
__device__ __forceinline__ void stage256x32(const unsigned short* __restrict__ g, size_t ldr,
                                            unsigned short* __restrict__ lds, int tid) {
#pragma unroll
  for (int r = 0; r < 2; ++r) {
    const int row = r * 128 + (tid >> 2);
    const int cb = (tid & 3) * 16;
    const int cs = cb ^ ((row & 8) << 2);
    gload16((const char*)g + (size_t)row * ldr * 2 + cs, (char*)lds + r * 8192 + tid * 16);
  }
}

// ---------- scores: r12-proven (unchanged) ----------
// scores[b][t][s] = sum_h outp[t][b][h] * mem[s][b][h]

__global__ __launch_bounds__(512, 1) void k_scores(const unsigned short* __restrict__ oH,
                                                   const unsigned short* __restrict__ oL,
                                                   const unsigned short* __restrict__ mH,
                                                   const unsigned short* __restrict__ mL,
                                                   float* __restrict__ attn) {
  __shared__ unsigned short AsH[2][256 * 32], AsL[2][256 * 32];
  __shared__ unsigned short BsH[2][256 * 32], BsL[2][256 * 32];
  const int tid = threadIdx.x, lane = tid & 63, wv = tid >> 6;
  const int wr = wv >> 2, wc = wv & 3;
  const int swz = xcd_swz(blockIdx.x, 512);
  const int bs = (swz & 7) * 256;
  const int bt = ((swz >> 3) & 3) * 256;
  const int b = swz >> 5;
  const f32x4 fz = {0.f, 0.f, 0.f, 0.f};
  f32x4 acc[8][4];
#pragma unroll
  for (int i = 0; i < 8; ++i)
#pragma unroll
    for (int j = 0; j < 4; ++j) acc[i][j] = fz;

  const unsigned short* AgH = oH + ((size_t)b * Tn + bt) * Hn;
  const unsigned short* AgL = oL + ((size_t)b * Tn + bt) * Hn;
  const unsigned short* BgH = mH + ((size_t)b * Sn + bs) * Hn;
  const unsigned short* BgL = mL + ((size_t)b * Sn + bs) * Hn;
  const int r16 = lane & 15, khB = (lane >> 4) * 16;
  const int NK = Hn / 32;  // 32

  stage256x32(AgH, Hn, AsH[0], tid);
  stage256x32(AgL, Hn, AsL[0], tid);
  stage256x32(BgH, Hn, BsH[0], tid);
  stage256x32(BgL, Hn, BsL[0], tid);

  for (int t = 0; t < NK; ++t) {
    const int cur = t & 1;
    asm volatile("s_waitcnt vmcnt(0)" ::: "memory");
    __builtin_amdgcn_s_barrier();

    const bool st = (t + 1) < NK;
    const int k1 = (t + 1) * 32;
    const char* ABh = (const char*)AsH[cur];
    const char* ABl = (const char*)AsL[cur];
    const char* BBh = (const char*)BsH[cur];
    const char* BBl = (const char*)BsL[cur];

    if (st) {
      stage256x32(AgH + k1, Hn, AsH[cur ^ 1], tid);
      stage256x32(AgL + k1, Hn, AsL[cur ^ 1], tid);
    }

    bf16x8 bh[2][2], bl[2][2];
#pragma unroll
    for (int nq = 0; nq < 2; ++nq)
#pragma unroll
      for (int fj = 0; fj < 2; ++fj) {
        const int rb = wc * 64 + nq * 32 + fj * 16 + r16;
        const int off = rb * 64 + (khB ^ ((rb & 8) << 2));
        bh[nq][fj] = *(const bf16x8*)(BBh + off);
        bl[nq][fj] = *(const bf16x8*)(BBl + off);
      }
    bf16x8 ah0[4], al0[4];
#pragma unroll
    for (int fi = 0; fi < 4; ++fi) {
      const int ra = wr * 128 + fi * 16 + r16;
      const int off = ra * 64 + (khB ^ ((ra & 8) << 2));
      ah0[fi] = *(const bf16x8*)(ABh + off);
      al0[fi] = *(const bf16x8*)(ABl + off);
    }
    __builtin_amdgcn_s_setprio(1);
#pragma unroll
    for (int nq = 0; nq < 2; ++nq)
#pragma unroll
      for (int fj = 0; fj < 2; ++fj)
#pragma unroll
        for (int fi = 0; fi < 4; ++fi) {
          f32x4& a = acc[fi][nq * 2 + fj];
          a = mfma16(ah0[fi], bh[nq][fj], a);
          a = mfma16(ah0[fi], bl[nq][fj], a);
          a = mfma16(al0[fi], bh[nq][fj], a);
        }
    __builtin_amdgcn_s_setprio(0);

    if (st) {
      stage256x32(BgH + k1, Hn, BsH[cur ^ 1], tid);
      stage256x32(BgL + k1, Hn, BsL[cur ^ 1], tid);
    }
    bf16x8 ah1[4], al1[4];
#pragma unroll
    for (int fi = 0; fi < 4; ++fi) {
      const int ra = wr * 128 + 64 + fi * 16 + r16;
      const int off = ra * 64 + (khB ^ ((ra & 8) << 2));
      ah1[fi] = *(const bf16x8*)(ABh + off);
      al1[fi] = *(const bf16x8*)(ABl + off);
    }
    __builtin_amdgcn_s_setprio(1);
#pragma unroll
    for (int nq = 0; nq < 2; ++nq)
#pragma unroll
      for (int fj = 0; fj < 2; ++fj)
#pragma unroll
        for (int fi = 0; fi < 4; ++fi) {
          f32x4& a = acc[4 + fi][nq * 2 + fj];
          a = mfma16(ah1[fi], bh[nq][fj], a);
          a = mfma16(ah1[fi], bl[nq][fj], a);
          a = mfma16(al1[fi], bh[nq][fj], a);
        }
    __builtin_amdgcn_s_setprio(0);
  }

  const int rq = (lane >> 4) * 4;
  float* obase = attn + (size_t)b * Tn * Sn;
#pragma unroll
  for (int i = 0; i < 8; ++i) {
    const int m_off = wr * 128 + (i >> 2) * 64 + (i & 3) * 16;
#pragma unroll
    for (int q = 0; q < 4; ++q) {
      const int t = bt + m_off + rq + q;
#pragma unroll
      for (int j = 0; j < 4; ++j) {
        const int s = bs + wc * 64 + (j >> 1) * 32 + (j & 1) * 16 + r16;
        obase[(size_t)t * Sn + s] = acc[i][j][q];
      }
    }
  }
}

// ---------- softmax (unchanged) ----------

__global__ __launch_bounds__(256) void k_softmax(float* __restrict__ attn,
                                                 const unsigned char* __restrict__ mask,
                                                 unsigned short* __restrict__ attnbf) {
  const int row = blockIdx.x;  // b*T + t
  float* p = attn + (size_t)row * Sn;
  const unsigned char* mrow = mask + (size_t)row * Sn;
  const int tid = threadIdx.x;
  const int lane = tid & 63;
  const int wv = tid >> 6;
  const float4 a = *(const float4*)(p + tid * 8);
  const float4 c = *(const float4*)(p + tid * 8 + 4);
  const unsigned long long mv = *(const unsigned long long*)(mrow + tid * 8);
  float x[8] = {a.x, a.y, a.z, a.w, c.x, c.y, c.z, c.w};
#pragma unroll
  for (int j = 0; j < 8; ++j)
    if ((mv >> (8 * j)) & 0xffull) x[j] = -INFINITY;
  float mx = x[0];
#pragma unroll
  for (int j = 1; j < 8; ++j) mx = fmaxf(mx, x[j]);
#pragma unroll
  for (int off = 32; off; off >>= 1) mx = fmaxf(mx, __shfl_xor(mx, off, 64));
  __shared__ float redmax[4], redsum[4];
  if (lane == 0) redmax[wv] = mx;
  __syncthreads();
  mx = fmaxf(fmaxf(redmax[0], redmax[1]), fmaxf(redmax[2], redmax[3]));
  float e[8];
  float s = 0.f;
#pragma unroll
  for (int j = 0; j < 8; ++j) {
    e[j] = __expf(x[j] - mx);
    s += e[j];
  }
#pragma unroll
  for (int off = 32; off; off >>= 1) s += __shfl_xor(s, off, 64);
  if (lane == 0) redsum[wv] = s;
  __syncthreads();
  s = redsum[0] + redsum[1] + redsum[2] + redsum[3];
  const float inv = 1.0f / s;
  float o[8];
#pragma unroll
  for (int j = 0; j < 8; ++j) o[j] = e[j] * inv;
  float4 o0 = {o[0], o[1], o[2], o[3]};
  float4 o1 = {o[4], o[5], o[6], o[7]};
  *(float4*)(p + tid * 8) = o0;
  *(float4*)(p + tid * 8 + 4) = o1;
  u16x8 ub;
#pragma unroll
  for (int j = 0; j < 8; ++j) ub[j] = f2bf(o[j]);
  *(u16x8*)(attnbf + (size_t)row * Sn + tid * 8) = ub;
}

// ---------- context: 256^2, BK=32, single bf16, 64KB LDS -> 2 blocks/CU ----------
// ctx[b][t][h] = sum_s attnbf[b][t][s] * memT[b][h][s]

__global__ __launch_bounds__(512, 2) void k_context(const unsigned short* __restrict__ attnbf,
                                                    const unsigned short* __restrict__ memT,
                                                    unsigned short* __restrict__ ctxB) {
  __shared__ unsigned short As[2][256 * 32], Bs[2][256 * 32];
  const int tid = threadIdx.x, lane = tid & 63, wv = tid >> 6;
  const int wr = wv >> 2, wc = wv & 3;
  const int swz = xcd_swz(blockIdx.x, 256);
  const int bh = (swz & 3) * 256;
  const int bt = ((swz >> 2) & 3) * 256;
  const int b = swz >> 4;
  const f32x4 fz = {0.f, 0.f, 0.f, 0.f};
  f32x4 acc[8][4];
#pragma unroll
  for (int i = 0; i < 8; ++i)
#pragma unroll
    for (int j = 0; j < 4; ++j) acc[i][j] = fz;

  const unsigned short* Ag = attnbf + ((size_t)b * Tn + bt) * Sn;
  const unsigned short* Bg = memT + ((size_t)b * Hn + bh) * Sn;
  const int r16 = lane & 15, khB = (lane >> 4) * 16;
  const int NK = Sn / 32;  // 64

  stage256x32(Ag, Sn, As[0], tid);
  stage256x32(Bg, Sn, Bs[0], tid);

  for (int t = 0; t < NK; ++t) {
    const int cur = t & 1;
    if (t + 1 < NK) {
      const int k0 = (t + 1) * 32;
      stage256x32(Ag + k0, Sn, As[cur ^ 1], tid);
      stage256x32(Bg + k0, Sn, Bs[cur ^ 1], tid);
      asm volatile("s_waitcnt vmcnt(4)" ::: "memory");  // tile t's 4 loads landed
    } else {
      asm volatile("s_waitcnt vmcnt(0)" ::: "memory");
    }
    __builtin_amdgcn_s_barrier();

    const char* Ab = (const char*)As[cur];
    const char* Bb = (const char*)Bs[cur];
    bf16x8 bb[2][2];  // [nq][fj]
#pragma unroll
    for (int nq = 0; nq < 2; ++nq)
#pragma unroll
      for (int fj = 0; fj < 2; ++fj) {
        const int rb = wc * 64 + nq * 32 + fj * 16 + r16;
        const int off = rb * 64 + (khB ^ ((rb & 8) << 2));
        bb[nq][fj] = *(const bf16x8*)(Bb + off);
      }
#pragma unroll
    for (int mq = 0; mq < 2; ++mq) {
      bf16x8 aa[4];
#pragma unroll
      for (int fi = 0; fi < 4; ++fi) {
        const int ra = wr * 128 + mq * 64 + fi * 16 + r16;
        const int off = ra * 64 + (khB ^ ((ra & 8) << 2));
        aa[fi] = *(const bf16x8*)(Ab + off);
      }
      __builtin_amdgcn_s_setprio(1);
#pragma unroll
      for (int nq = 0; nq < 2; ++nq)
#pragma unroll
        for (int fj = 0; fj < 2; ++fj)
#pragma unroll
          for (int fi = 0; fi < 4; ++fi) {
            f32x4& a = acc[mq * 4 + fi][nq * 2 + fj];
            a = mfma16(aa[fi], bb[nq][fj], a);
          }
      __builtin_amdgcn_s_setprio(0);
    }
    __builtin_amdgcn_s_barrier();
  }
  const int rq = (lane >> 4) * 4;
#pragma unroll
  for (int i = 0; i < 8; ++i) {
    const int m_off = wr * 128 + (i >> 2) * 64 + (i & 3) * 16;
#pragma unroll
    for (int q = 0; q < 4; ++q) {
      const int t = bt + m_off + rq + q;
#pragma unroll
      for (int j = 0; j < 4; ++j) {
        const int h = bh + wc * 64 + (j >> 1) * 32 + (j & 1) * 16 + r16;
        ctxB[((size_t)b * Tn + t) * Hn + h] = f2bf(acc[i][j][q]);
      }
    }
  }
}

// ---------- final: 256^2, BK=32, single bf16, tanh epilogue, 64KB LDS -> 2 blocks/CU ----------
// out[t][b][h] = tanh( sum_k [ctxB|outpH][b*T+t][k] * W[h][k] + bias[h] )

__global__ __launch_bounds__(512, 2) void k_final(const unsigned short* __restrict__ ctxB,
                                                  const unsigned short* __restrict__ outpH,
                                                  const unsigned short* __restrict__ Wbf,
                                                  const float* __restrict__ bias,
                                                  float* __restrict__ out) {
  __shared__ unsigned short As[2][256 * 32], Bs[2][256 * 32];
  const int tid = threadIdx.x, lane = tid & 63, wv = tid >> 6;
  const int wr = wv >> 2, wc = wv & 3;
  const int swz = xcd_swz(blockIdx.x, 256);
  const int bh = (swz & 3) * 256;
  const int bm = (swz >> 2) * 256;
  const f32x4 fz = {0.f, 0.f, 0.f, 0.f};
  f32x4 acc[8][4];
#pragma unroll
  for (int i = 0; i < 8; ++i)
#pragma unroll
    for (int j = 0; j < 4; ++j) acc[i][j] = fz;

  const int r16 = lane & 15, khB = (lane >> 4) * 16;
  const int NK = (2 * Hn) / 32;  // 64
  auto Asrc = [&](int tt) -> const unsigned short* {
    return (tt < 32) ? (ctxB + (size_t)bm * Hn + tt * 32)
                     : (outpH + (size_t)bm * Hn + (tt - 32) * 32);
  };
  const unsigned short* Bg = Wbf + (size_t)bh * (2 * Hn);

  stage256x32(Asrc(0), Hn, As[0], tid);
  stage256x32(Bg, 2 * Hn, Bs[0], tid);

  for (int t = 0; t < NK; ++t) {
    const int cur = t & 1;
    if (t + 1 < NK) {
      stage256x32(Asrc(t + 1), Hn, As[cur ^ 1], tid);
      stage256x32(Bg + (t + 1) * 32, 2 * Hn, Bs[cur ^ 1], tid);
      asm volatile("s_waitcnt vmcnt(4)" ::: "memory");
    } else {
      asm volatile("s_waitcnt vmcnt(0)" ::: "memory");
    }
    __builtin_amdgcn_s_barrier();

    const char* Ab = (const char*)As[cur];
    const char* Bb = (const char*)Bs[cur];
    bf16x8 bb[2][2];
#pragma unroll
    for (int nq = 0; nq < 2; ++nq)
#pragma unroll
      for (int fj = 0; fj < 2; ++fj) {
        const int rb = wc * 64 + nq * 32 + fj * 16 + r16;
        const int off = rb * 64 + (khB ^ ((rb & 8) << 2));
        bb[nq][fj] = *(const bf16x8*)(Bb + off);
      }
#pragma unroll
    for (int mq = 0; mq < 2; ++mq) {
      bf16x8 aa[4];
#pragma unroll
      for (int fi = 0; fi < 4; ++fi) {
        const int ra = wr * 128 + mq * 64 + fi * 16 + r16;
        const int off = ra * 64 + (khB ^ ((ra & 8) << 2));
        aa[fi] = *(const bf16x8*)(Ab + off);
      }
      __builtin_amdgcn_s_setprio(1);
#pragma unroll
      for (int nq = 0; nq < 2; ++nq)
#pragma unroll
        for (int fj = 0; fj < 2; ++fj)
#pragma unroll
          for (int fi = 0; fi < 4; ++fi) {
            f32x4& a = acc[mq * 4 + fi][nq * 2 + fj];
            a = mfma16(aa[fi], bb[nq][fj], a);
          }
      __builtin_amdgcn_s_setprio(0);
    }
    __builtin_amdgcn_s_barrier();
  }
  const int rq = (lane >> 4) * 4;
#pragma unroll
  for (int i = 0; i < 8; ++i) {
    const int m_off = wr * 128 + (i >> 2) * 64 + (i & 3) * 16;
#pragma unroll
    for (int q = 0; q < 4; ++q) {
      const int r = bm + m_off + rq + q;  // b*T + t
      const int b = r >> 10, t = r & (Tn - 1);
#pragma unroll
      for (int j = 0; j < 4; ++j) {
        const int h = bh + wc * 64 + (j >> 1) * 32 + (j & 1) * 16 + r16;
        out[((size_t)t * Bn + b) * Hn + h] = tanhf(acc[i][j][q] + bias[h]);
      }
    }
  }
}

extern "C" void kernel_launch(void* const* d_in, const int* in_sizes, int n_in,
                              void* d_out, int out_size, void* d_ws, size_t ws_size,
                              hipStream_t stream) {
  const float* outp = (const float*)d_in[0];
  const float* mem = (const float*)d_in[1];
  const unsigned char* mask = (const unsigned char*)d_in[2];
  const float* W = (const float*)d_in[3];
  const float* bias = (const float*)d_in[4];
  float* out = (float*)d_out;                // (T,B,H) f32
  float* attn = out + (size_t)Tn * Bn * Hn;  // (B,T,S) f32 (output 2)

  // workspace layout (all regions 16B-aligned)
  char* w = (char*)d_ws;
  unsigned short* memH  = (unsigned short*)(w);                        // [B][S][H] 64MB
  unsigned short* memL  = (unsigned short*)(w + ((size_t)64 << 20));   // [B][S][H] 64MB
  unsigned short* outpH = (unsigned short*)(w + ((size_t)128 << 20));  // [B][T][H] 32MB
  unsigned short* outpL = (unsigned short*)(w + ((size_t)160 << 20));  // [B][T][H] 32MB
  unsigned short* Wbf   = (unsigned short*)(w + ((size_t)192 << 20));  // [H][2H]    4MB
  unsigned short* memT  = (unsigned short*)(w + ((size_t)196 << 20));  // [B][H][S] 64MB
  // aliases (written only after scores has consumed the originals):
  unsigned short* attnbf = memH;   // [B][T][S] 64MB (softmax..context)
  unsigned short* ctxB   = outpL;  // [B][T][H] 32MB (context..final)

  k_split_plane<<<dim3((Tn * Bn * Hn / 8) / 256), 256, 0, stream>>>(outp, outpH, outpL, Tn);
  k_split_mem3<<<dim3(Hn / 64, Sn / 64, Bn), 256, 0, stream>>>(mem, memH, memL, memT);
  k_cvt8<<<dim3((Hn * 2 * Hn / 8) / 256), 256, 0, stream>>>(W, Wbf, Hn * 2 * Hn / 8);

  k_scores<<<dim3(512), 512, 0, stream>>>(outpH, outpL, memH, memL, attn);
  k_softmax<<<dim3(Bn * Tn), 256, 0, stream>>>(attn, mask, attnbf);
  k_context<<<dim3(256), 512, 0, stream>>>(attnbf, memT, ctxB);
  k_final<<<dim3(256), 512, 0, stream>>>(ctxB, outpH, Wbf, bias, out);
}

// Round 16
// 515.587 us; speedup vs baseline: 1.0625x; 1.0625x over previous
//
#include <hip/hip_runtime.h>
#include <hip/hip_bf16.h>
#include <math.h>

#define Tn 1024
#define Bn 16
#define Hn 1024
#define Sn 2048

typedef __attribute__((ext_vector_type(8))) short bf16x8;
typedef __attribute__((ext_vector_type(8))) unsigned short u16x8;
typedef __attribute__((ext_vector_type(4))) float f32x4;

__device__ __forceinline__ unsigned short f2bf(float x) {
  unsigned u = __float_as_uint(x);
  u += 0x7fffu + ((u >> 16) & 1u);  // round-to-nearest-even to bf16
  return (unsigned short)(u >> 16);
}
__device__ __forceinline__ float bf2f(unsigned short h) {
  return __uint_as_float(((unsigned)h) << 16);
}

// async global->LDS, 16B per lane; LDS dest = wave-uniform base + lane*16
__device__ __forceinline__ void gload16(const void* g, void* l) {
  __builtin_amdgcn_global_load_lds((const __attribute__((address_space(1))) void*)g,
                                   (__attribute__((address_space(3))) void*)l, 16, 0, 0);
}

// XCD-chunked bijective blockIdx swizzle (nwg % 8 == 0)
__device__ __forceinline__ int xcd_swz(int bid, int nwg) {
  return (bid & 7) * (nwg >> 3) + (bid >> 3);
}

__device__ __forceinline__ f32x4 mfma16(bf16x8 a, bf16x8 b, f32x4 c) {
  return __builtin_amdgcn_mfma_f32_16x16x32_bf16(a, b, c, 0, 0, 0);
}

// ---------- conversion kernels ----------

__global__ __launch_bounds__(256) void k_split_plane(const float* __restrict__ src,
                                                     unsigned short* __restrict__ hiP,
                                                     unsigned short* __restrict__ loP,
                                                     int rows) {
  const int i = blockIdx.x * 256 + threadIdx.x;
  const int h8 = i & (Hn / 8 - 1);
  const int rem = i >> 7;
  const int b = rem & (Bn - 1);
  const int r = rem >> 4;
  const float4 a = *(const float4*)(src + (size_t)i * 8);
  const float4 c = *(const float4*)(src + (size_t)i * 8 + 4);
  const float v[8] = {a.x, a.y, a.z, a.w, c.x, c.y, c.z, c.w};
  u16x8 hv, lv;
#pragma unroll
  for (int j = 0; j < 8; ++j) {
    const unsigned short h = f2bf(v[j]);
    hv[j] = h;
    lv[j] = f2bf(v[j] - bf2f(h));
  }
  const size_t dst = ((size_t)b * rows + r) * Hn + h8 * 8;
  *(u16x8*)(hiP + dst) = hv;
  *(u16x8*)(loP + dst) = lv;
}

__global__ __launch_bounds__(256) void k_cvt8(const float* __restrict__ src,
                                              unsigned short* __restrict__ dst, int n8) {
  const int i = blockIdx.x * 256 + threadIdx.x;
  if (i >= n8) return;
  const float4 a = *(const float4*)(src + (size_t)i * 8);
  const float4 c = *(const float4*)(src + (size_t)i * 8 + 4);
  u16x8 u;
  u[0] = f2bf(a.x); u[1] = f2bf(a.y); u[2] = f2bf(a.z); u[3] = f2bf(a.w);
  u[4] = f2bf(c.x); u[5] = f2bf(c.y); u[6] = f2bf(c.z); u[7] = f2bf(c.w);
  *(u16x8*)(dst + (size_t)i * 8) = u;
}

// memH [B][S][H] bf16 -> memT [B][H][S] bf16, 64x64 LDS tile transpose
__global__ __launch_bounds__(256) void k_trH(const unsigned short* __restrict__ memH,
                                             unsigned short* __restrict__ memT) {
  __shared__ unsigned short L[64 * 72];
  const int t = threadIdx.x;
  const int h0 = blockIdx.x * 64, s0 = blockIdx.y * 64, b = blockIdx.z;
#pragma unroll
  for (int p = 0; p < 2; ++p) {
    const int fid = p * 256 + t;
    const int s_l = fid >> 3;
    const int c = fid & 7;
    const u16x8 v = *(const u16x8*)(memH + ((size_t)b * Sn + s0 + s_l) * Hn + h0 + c * 8);
#pragma unroll
    for (int e = 0; e < 8; ++e) L[(c * 8 + e) * 72 + s_l] = v[e];
  }
  __syncthreads();
#pragma unroll
  for (int p = 0; p < 2; ++p) {
    const int cid = p * 256 + t;
    const int h_l = cid >> 3;
    const int c = cid & 7;
    const u16x8 vv = *(const u16x8*)&L[h_l * 72 + c * 8];
    *(u16x8*)(memT + ((size_t)b * Hn + h0 + h_l) * Sn + s0 + c * 8) = vv;
  }
}

// ---------- staging (linear LDS dest, XOR-swizzled global source) ----------

// 256 rows x 64 cols bf16 (128B rows). swizzle: cbyte ^= (row&7)<<4
__device__ __forceinline__ void stage256x64(const unsigned short* __restrict__ g, size_t ldr,
                                            unsigned short* __restrict__ lds, int tid) {
#pragma unroll
  for (int r = 0; r < 4; ++r) {
    const int row = r * 64 + (tid >> 3);
    const int cb = (tid & 7) * 16;
    const int cs = cb ^ ((row & 7) << 4);
    gload16((const char*)g + (size_t)row * ldr * 2 + cs, (char*)lds + r * 8192 + tid * 16);
  }
}

// 256 rows x 32 cols bf16 (64B rows). swizzle: cbyte ^= (row&8)<<2 (measured 0-conflict)
__device__ __forceinline__ void stage256x32(const unsigned short* __restrict__ g, size_t ldr,
                                            unsigned short* __restrict__ lds, int tid) {
#pragma unroll
  for (int r = 0; r < 2; ++r) {
    const int row = r * 128 + (tid >> 2);
    const int cb = (tid & 3) * 16;
    const int cs = cb ^ ((row & 8) << 2);
    gload16((const char*)g + (size_t)row * ldr * 2 + cs, (char*)lds + r * 8192 + tid * 16);
  }
}

// ---------- scores: 256^2, BK=32, bf16x3, 16x16x32 MFMA, 1 barrier/tile, 24 reads ----------
// scores[b][t][s] = sum_h outp[t][b][h] * mem[s][b][h]

__global__ __launch_bounds__(512, 1) void k_scores(const unsigned short* __restrict__ oH,
                                                   const unsigned short* __restrict__ oL,
                                                   const unsigned short* __restrict__ mH,
                                                   const unsigned short* __restrict__ mL,
                                                   float* __restrict__ attn) {
  __shared__ unsigned short AsH[2][256 * 32], AsL[2][256 * 32];
  __shared__ unsigned short BsH[2][256 * 32], BsL[2][256 * 32];
  const int tid = threadIdx.x, lane = tid & 63, wv = tid >> 6;
  const int wr = wv >> 2, wc = wv & 3;
  const int swz = xcd_swz(blockIdx.x, 512);
  const int bs = (swz & 7) * 256;
  const int bt = ((swz >> 3) & 3) * 256;
  const int b = swz >> 5;
  const f32x4 fz = {0.f, 0.f, 0.f, 0.f};
  f32x4 acc[8][4];
#pragma unroll
  for (int i = 0; i < 8; ++i)
#pragma unroll
    for (int j = 0; j < 4; ++j) acc[i][j] = fz;

  const unsigned short* AgH = oH + ((size_t)b * Tn + bt) * Hn;
  const unsigned short* AgL = oL + ((size_t)b * Tn + bt) * Hn;
  const unsigned short* BgH = mH + ((size_t)b * Sn + bs) * Hn;
  const unsigned short* BgL = mL + ((size_t)b * Sn + bs) * Hn;
  const int r16 = lane & 15, khB = (lane >> 4) * 16;
  const int NK = Hn / 32;  // 32

  stage256x32(AgH, Hn, AsH[0], tid);
  stage256x32(AgL, Hn, AsL[0], tid);
  stage256x32(BgH, Hn, BsH[0], tid);
  stage256x32(BgL, Hn, BsL[0], tid);

  for (int t = 0; t < NK; ++t) {
    const int cur = t & 1;
    asm volatile("s_waitcnt vmcnt(0)" ::: "memory");
    __builtin_amdgcn_s_barrier();

    const bool st = (t + 1) < NK;
    const int k1 = (t + 1) * 32;
    const char* ABh = (const char*)AsH[cur];
    const char* ABl = (const char*)AsL[cur];
    const char* BBh = (const char*)BsH[cur];
    const char* BBl = (const char*)BsL[cur];

    if (st) {
      stage256x32(AgH + k1, Hn, AsH[cur ^ 1], tid);
      stage256x32(AgL + k1, Hn, AsL[cur ^ 1], tid);
    }

    bf16x8 bh[2][2], bl[2][2];
#pragma unroll
    for (int nq = 0; nq < 2; ++nq)
#pragma unroll
      for (int fj = 0; fj < 2; ++fj) {
        const int rb = wc * 64 + nq * 32 + fj * 16 + r16;
        const int off = rb * 64 + (khB ^ ((rb & 8) << 2));
        bh[nq][fj] = *(const bf16x8*)(BBh + off);
        bl[nq][fj] = *(const bf16x8*)(BBl + off);
      }
    bf16x8 ah0[4], al0[4];
#pragma unroll
    for (int fi = 0; fi < 4; ++fi) {
      const int ra = wr * 128 + fi * 16 + r16;
      const int off = ra * 64 + (khB ^ ((ra & 8) << 2));
      ah0[fi] = *(const bf16x8*)(ABh + off);
      al0[fi] = *(const bf16x8*)(ABl + off);
    }
    __builtin_amdgcn_s_setprio(1);
#pragma unroll
    for (int nq = 0; nq < 2; ++nq)
#pragma unroll
      for (int fj = 0; fj < 2; ++fj)
#pragma unroll
        for (int fi = 0; fi < 4; ++fi) {
          f32x4& a = acc[fi][nq * 2 + fj];
          a = mfma16(ah0[fi], bh[nq][fj], a);
          a = mfma16(ah0[fi], bl[nq][fj], a);
          a = mfma16(al0[fi], bh[nq][fj], a);
        }
    __builtin_amdgcn_s_setprio(0);

    if (st) {
      stage256x32(BgH + k1, Hn, BsH[cur ^ 1], tid);
      stage256x32(BgL + k1, Hn, BsL[cur ^ 1], tid);
    }
    bf16x8 ah1[4], al1[4];
#pragma unroll
    for (int fi = 0; fi < 4; ++fi) {
      const int ra = wr * 128 + 64 + fi * 16 + r16;
      const int off = ra * 64 + (khB ^ ((ra & 8) << 2));
      ah1[fi] = *(const bf16x8*)(ABh + off);
      al1[fi] = *(const bf16x8*)(ABl + off);
    }
    __builtin_amdgcn_s_setprio(1);
#pragma unroll
    for (int nq = 0; nq < 2; ++nq)
#pragma unroll
      for (int fj = 0; fj < 2; ++fj)
#pragma unroll
        for (int fi = 0; fi < 4; ++fi) {
          f32x4& a = acc[4 + fi][nq * 2 + fj];
          a = mfma16(ah1[fi], bh[nq][fj], a);
          a = mfma16(ah1[fi], bl[nq][fj], a);
          a = mfma16(al1[fi], bh[nq][fj], a);
        }
    __builtin_amdgcn_s_setprio(0);
  }

  const int rq = (lane >> 4) * 4;
  float* obase = attn + (size_t)b * Tn * Sn;
#pragma unroll
  for (int i = 0; i < 8; ++i) {
    const int m_off = wr * 128 + (i >> 2) * 64 + (i & 3) * 16;
#pragma unroll
    for (int q = 0; q < 4; ++q) {
      const int t = bt + m_off + rq + q;
#pragma unroll
      for (int j = 0; j < 4; ++j) {
        const int s = bs + wc * 64 + (j >> 1) * 32 + (j & 1) * 16 + r16;
        obase[(size_t)t * Sn + s] = acc[i][j][q];
      }
    }
  }
}

// ---------- softmax ----------

__global__ __launch_bounds__(256) void k_softmax(float* __restrict__ attn,
                                                 const unsigned char* __restrict__ mask,
                                                 unsigned short* __restrict__ attnbf) {
  const int row = blockIdx.x;  // b*T + t
  float* p = attn + (size_t)row * Sn;
  const unsigned char* mrow = mask + (size_t)row * Sn;
  const int tid = threadIdx.x;
  const int lane = tid & 63;
  const int wv = tid >> 6;
  const float4 a = *(const float4*)(p + tid * 8);
  const float4 c = *(const float4*)(p + tid * 8 + 4);
  const unsigned long long mv = *(const unsigned long long*)(mrow + tid * 8);
  float x[8] = {a.x, a.y, a.z, a.w, c.x, c.y, c.z, c.w};
#pragma unroll
  for (int j = 0; j < 8; ++j)
    if ((mv >> (8 * j)) & 0xffull) x[j] = -INFINITY;
  float mx = x[0];
#pragma unroll
  for (int j = 1; j < 8; ++j) mx = fmaxf(mx, x[j]);
#pragma unroll
  for (int off = 32; off; off >>= 1) mx = fmaxf(mx, __shfl_xor(mx, off, 64));
  __shared__ float redmax[4], redsum[4];
  if (lane == 0) redmax[wv] = mx;
  __syncthreads();
  mx = fmaxf(fmaxf(redmax[0], redmax[1]), fmaxf(redmax[2], redmax[3]));
  float e[8];
  float s = 0.f;
#pragma unroll
  for (int j = 0; j < 8; ++j) {
    e[j] = __expf(x[j] - mx);
    s += e[j];
  }
#pragma unroll
  for (int off = 32; off; off >>= 1) s += __shfl_xor(s, off, 64);
  if (lane == 0) redsum[wv] = s;
  __syncthreads();
  s = redsum[0] + redsum[1] + redsum[2] + redsum[3];
  const float inv = 1.0f / s;
  float o[8];
#pragma unroll
  for (int j = 0; j < 8; ++j) o[j] = e[j] * inv;
  float4 o0 = {o[0], o[1], o[2], o[3]};
  float4 o1 = {o[4], o[5], o[6], o[7]};
  *(float4*)(p + tid * 8) = o0;
  *(float4*)(p + tid * 8 + 4) = o1;
  u16x8 ub;
#pragma unroll
  for (int j = 0; j < 8; ++j) ub[j] = f2bf(o[j]);
  *(u16x8*)(attnbf + (size_t)row * Sn + tid * 8) = ub;
}

// ---------- context: 256^2, BK=64, single bf16 (r12-proven 2-barrier) ----------
// ctx[b][t][h] = sum_s attnbf[b][t][s] * memT[b][h][s]

__global__ __launch_bounds__(512, 2) void k_context(const unsigned short* __restrict__ attnbf,
                                                    const unsigned short* __restrict__ memT,
                                                    unsigned short* __restrict__ ctxB) {
  __shared__ unsigned short As[2][256 * 64], Bs[2][256 * 64];
  const int tid = threadIdx.x, lane = tid & 63, wv = tid >> 6;
  const int wr = wv >> 2, wc = wv & 3;
  const int swz = xcd_swz(blockIdx.x, 256);
  const int bh = (swz & 3) * 256;
  const int bt = ((swz >> 2) & 3) * 256;
  const int b = swz >> 4;
  const f32x4 fz = {0.f, 0.f, 0.f, 0.f};
  f32x4 acc[8][4];
#pragma unroll
  for (int i = 0; i < 8; ++i)
#pragma unroll
    for (int j = 0; j < 4; ++j) acc[i][j] = fz;

  const unsigned short* Ag = attnbf + ((size_t)b * Tn + bt) * Sn;
  const unsigned short* Bg = memT + ((size_t)b * Hn + bh) * Sn;
  const int r16 = lane & 15, khB = (lane >> 4) * 16;
  const int NK = Sn / 64;  // 32

  stage256x64(Ag, Sn, As[0], tid);
  stage256x64(Bg, Sn, Bs[0], tid);

  for (int t = 0; t < NK; ++t) {
    const int cur = t & 1;
    if (t + 1 < NK) {
      const int k0 = (t + 1) * 64;
      stage256x64(Ag + k0, Sn, As[cur ^ 1], tid);
      stage256x64(Bg + k0, Sn, Bs[cur ^ 1], tid);
      asm volatile("s_waitcnt vmcnt(8)" ::: "memory");
    } else {
      asm volatile("s_waitcnt vmcnt(0)" ::: "memory");
    }
    __builtin_amdgcn_s_barrier();

    const char* Ab = (const char*)As[cur];
    const char* Bb = (const char*)Bs[cur];
    bf16x8 bb[2][2][2];  // [nq][fj][ks]
#pragma unroll
    for (int nq = 0; nq < 2; ++nq)
#pragma unroll
      for (int fj = 0; fj < 2; ++fj) {
        const int rb = wc * 64 + nq * 32 + fj * 16 + r16;
#pragma unroll
        for (int ks = 0; ks < 2; ++ks) {
          const int cb = ks * 64 + khB;
          bb[nq][fj][ks] = *(const bf16x8*)(Bb + rb * 128 + (cb ^ ((rb & 7) << 4)));
        }
      }
#pragma unroll
    for (int mq = 0; mq < 2; ++mq) {
      bf16x8 aa[4][2];
#pragma unroll
      for (int fi = 0; fi < 4; ++fi) {
        const int ra = wr * 128 + mq * 64 + fi * 16 + r16;
#pragma unroll
        for (int ks = 0; ks < 2; ++ks) {
          const int cb = ks * 64 + khB;
          aa[fi][ks] = *(const bf16x8*)(Ab + ra * 128 + (cb ^ ((ra & 7) << 4)));
        }
      }
      __builtin_amdgcn_s_setprio(1);
#pragma unroll
      for (int nq = 0; nq < 2; ++nq)
#pragma unroll
        for (int fj = 0; fj < 2; ++fj)
#pragma unroll
          for (int fi = 0; fi < 4; ++fi)
#pragma unroll
            for (int ks = 0; ks < 2; ++ks) {
              f32x4& a = acc[mq * 4 + fi][nq * 2 + fj];
              a = mfma16(aa[fi][ks], bb[nq][fj][ks], a);
            }
      __builtin_amdgcn_s_setprio(0);
    }
    __builtin_amdgcn_s_barrier();
  }
  const int rq = (lane >> 4) * 4;
#pragma unroll
  for (int i = 0; i < 8; ++i) {
    const int m_off = wr * 128 + (i >> 2) * 64 + (i & 3) * 16;
#pragma unroll
    for (int q = 0; q < 4; ++q) {
      const int t = bt + m_off + rq + q;
#pragma unroll
      for (int j = 0; j < 4; ++j) {
        const int h = bh + wc * 64 + (j >> 1) * 32 + (j & 1) * 16 + r16;
        ctxB[((size_t)b * Tn + t) * Hn + h] = f2bf(acc[i][j][q]);
      }
    }
  }
}

// ---------- final: 256^2, BK=64, single bf16, tanh epilogue (r12-proven 2-barrier) ----------
// out[t][b][h] = tanh( sum_k [ctxB|outpH][b*T+t][k] * W[h][k] + bias[h] )

__global__ __launch_bounds__(512, 2) void k_final(const unsigned short* __restrict__ ctxB,
                                                  const unsigned short* __restrict__ outpH,
                                                  const unsigned short* __restrict__ Wbf,
                                                  const float* __restrict__ bias,
                                                  float* __restrict__ out) {
  __shared__ unsigned short As[2][256 * 64], Bs[2][256 * 64];
  const int tid = threadIdx.x, lane = tid & 63, wv = tid >> 6;
  const int wr = wv >> 2, wc = wv & 3;
  const int swz = xcd_swz(blockIdx.x, 256);
  const int bh = (swz & 3) * 256;
  const int bm = (swz >> 2) * 256;
  const f32x4 fz = {0.f, 0.f, 0.f, 0.f};
  f32x4 acc[8][4];
#pragma unroll
  for (int i = 0; i < 8; ++i)
#pragma unroll
    for (int j = 0; j < 4; ++j) acc[i][j] = fz;

  const int r16 = lane & 15, khB = (lane >> 4) * 16;
  const int NK = (2 * Hn) / 64;  // 32
  auto Asrc = [&](int tt) -> const unsigned short* {
    return (tt < 16) ? (ctxB + (size_t)bm * Hn + tt * 64)
                     : (outpH + (size_t)bm * Hn + (tt - 16) * 64);
  };
  const unsigned short* Bg = Wbf + (size_t)bh * (2 * Hn);

  stage256x64(Asrc(0), Hn, As[0], tid);
  stage256x64(Bg, 2 * Hn, Bs[0], tid);

  for (int t = 0; t < NK; ++t) {
    const int cur = t & 1;
    if (t + 1 < NK) {
      stage256x64(Asrc(t + 1), Hn, As[cur ^ 1], tid);
      stage256x64(Bg + (t + 1) * 64, 2 * Hn, Bs[cur ^ 1], tid);
      asm volatile("s_waitcnt vmcnt(8)" ::: "memory");
    } else {
      asm volatile("s_waitcnt vmcnt(0)" ::: "memory");
    }
    __builtin_amdgcn_s_barrier();

    const char* Ab = (const char*)As[cur];
    const char* Bb = (const char*)Bs[cur];
    bf16x8 bb[2][2][2];
#pragma unroll
    for (int nq = 0; nq < 2; ++nq)
#pragma unroll
      for (int fj = 0; fj < 2; ++fj) {
        const int rb = wc * 64 + nq * 32 + fj * 16 + r16;
#pragma unroll
        for (int ks = 0; ks < 2; ++ks) {
          const int cb = ks * 64 + khB;
          bb[nq][fj][ks] = *(const bf16x8*)(Bb + rb * 128 + (cb ^ ((rb & 7) << 4)));
        }
      }
#pragma unroll
    for (int mq = 0; mq < 2; ++mq) {
      bf16x8 aa[4][2];
#pragma unroll
      for (int fi = 0; fi < 4; ++fi) {
        const int ra = wr * 128 + mq * 64 + fi * 16 + r16;
#pragma unroll
        for (int ks = 0; ks < 2; ++ks) {
          const int cb = ks * 64 + khB;
          aa[fi][ks] = *(const bf16x8*)(Ab + ra * 128 + (cb ^ ((ra & 7) << 4)));
        }
      }
      __builtin_amdgcn_s_setprio(1);
#pragma unroll
      for (int nq = 0; nq < 2; ++nq)
#pragma unroll
        for (int fj = 0; fj < 2; ++fj)
#pragma unroll
          for (int fi = 0; fi < 4; ++fi)
#pragma unroll
            for (int ks = 0; ks < 2; ++ks) {
              f32x4& a = acc[mq * 4 + fi][nq * 2 + fj];
              a = mfma16(aa[fi][ks], bb[nq][fj][ks], a);
            }
      __builtin_amdgcn_s_setprio(0);
    }
    __builtin_amdgcn_s_barrier();
  }
  const int rq = (lane >> 4) * 4;
#pragma unroll
  for (int i = 0; i < 8; ++i) {
    const int m_off = wr * 128 + (i >> 2) * 64 + (i & 3) * 16;
#pragma unroll
    for (int q = 0; q < 4; ++q) {
      const int r = bm + m_off + rq + q;  // b*T + t
      const int b = r >> 10, t = r & (Tn - 1);
#pragma unroll
      for (int j = 0; j < 4; ++j) {
        const int h = bh + wc * 64 + (j >> 1) * 32 + (j & 1) * 16 + r16;
        out[((size_t)t * Bn + b) * Hn + h] = tanhf(acc[i][j][q] + bias[h]);
      }
    }
  }
}

extern "C" void kernel_launch(void* const* d_in, const int* in_sizes, int n_in,
                              void* d_out, int out_size, void* d_ws, size_t ws_size,
                              hipStream_t stream) {
  const float* outp = (const float*)d_in[0];
  const float* mem = (const float*)d_in[1];
  const unsigned char* mask = (const unsigned char*)d_in[2];
  const float* W = (const float*)d_in[3];
  const float* bias = (const float*)d_in[4];
  float* out = (float*)d_out;                // (T,B,H) f32
  float* attn = out + (size_t)Tn * Bn * Hn;  // (B,T,S) f32 (output 2)

  // workspace: peak 196 MB with aliasing (all regions 16B-aligned)
  char* w = (char*)d_ws;
  unsigned short* memH  = (unsigned short*)(w);                        // [B][S][H] 64MB
  unsigned short* memL  = (unsigned short*)(w + ((size_t)64 << 20));   // [B][S][H] 64MB
  unsigned short* outpH = (unsigned short*)(w + ((size_t)128 << 20));  // [B][T][H] 32MB
  unsigned short* outpL = (unsigned short*)(w + ((size_t)160 << 20));  // [B][T][H] 32MB
  unsigned short* Wbf   = (unsigned short*)(w + ((size_t)192 << 20));  // [H][2H]    4MB
  // aliases (written only after scores has consumed the originals):
  unsigned short* memT   = memL;   // [B][H][S] 64MB (trH..context)
  unsigned short* attnbf = memH;   // [B][T][S] 64MB (softmax..context)
  unsigned short* ctxB   = outpL;  // [B][T][H] 32MB (context..final)

  k_split_plane<<<dim3((Tn * Bn * Hn / 8) / 256), 256, 0, stream>>>(outp, outpH, outpL, Tn);
  k_split_plane<<<dim3((Sn * Bn * Hn / 8) / 256), 256, 0, stream>>>(mem, memH, memL, Sn);
  k_cvt8<<<dim3((Hn * 2 * Hn / 8) / 256), 256, 0, stream>>>(W, Wbf, Hn * 2 * Hn / 8);

  k_scores<<<dim3(512), 512, 0, stream>>>(outpH, outpL, memH, memL, attn);
  k_trH<<<dim3(Hn / 64, Sn / 64, Bn), 256, 0, stream>>>(memH, memT);
  k_softmax<<<dim3(Bn * Tn), 256, 0, stream>>>(attn, mask, attnbf);
  k_context<<<dim3(256), 512, 0, stream>>>(attnbf, memT, ctxB);
  k_final<<<dim3(256), 512, 0, stream>>>(ctxB, outpH, Wbf, bias, out);
}